// Round 9
// baseline (124.928 us; speedup 1.0000x reference)
//
#include <hip/hip_runtime.h>

typedef __attribute__((ext_vector_type(4))) float  f4;
typedef __attribute__((ext_vector_type(2))) float  f2;
typedef __attribute__((ext_vector_type(8))) short  short8;
typedef __attribute__((ext_vector_type(4))) float  f32x4;
typedef __attribute__((ext_vector_type(2))) unsigned int u32x2;

static __device__ __forceinline__ unsigned short f2bf(float f) {
    unsigned u = __builtin_bit_cast(unsigned, f);
    unsigned r = (u + 0x7FFFu + ((u >> 16) & 1u)) >> 16;   // RNE
    return (unsigned short)r;
}
static __device__ __forceinline__ float bf2f(unsigned short h) {
    return __builtin_bit_cast(float, ((unsigned)h) << 16);
}

// ---------------- K0: WhT[d][c]=bf16(g*Wh[c][d]); gb=g*bh; WfgT hi/lo split ----------------
__global__ __launch_bounds__(256) void k_setup(const float* __restrict__ Wh,
                                               const float* __restrict__ bh,
                                               const float* __restrict__ Wf,
                                               const float* __restrict__ Wg,
                                               const float* __restrict__ gamma,
                                               unsigned short* __restrict__ WhT,
                                               float* __restrict__ gb,
                                               unsigned short* __restrict__ Wfg_hi,
                                               unsigned short* __restrict__ Wfg_lo) {
    __shared__ float T[8 * 260];
    const int t = threadIdx.x, b = blockIdx.x;
    const float g = gamma[0];
    if (b < 32) {
        const int c0 = b * 8;
        const int cr = t >> 5, q = t & 31;
        f4 v0 = *(const f4*)(Wh + (c0 + cr) * 256 + q * 8);
        f4 v1 = *(const f4*)(Wh + (c0 + cr) * 256 + q * 8 + 4);
        *(f4*)(T + cr * 260 + q * 8)     = v0;
        *(f4*)(T + cr * 260 + q * 8 + 4) = v1;
        __syncthreads();
        short8 o;
        #pragma unroll
        for (int j = 0; j < 8; ++j) o[j] = (short)f2bf(g * T[j * 260 + t]);
        *(short8*)(WhT + t * 256 + c0) = o;
    } else {
        gb[t] = g * bh[t];
        const int n = t >> 2, cq = t & 3;
        const float* Wsrc = (n < 32) ? Wf : Wg;
        const int nn = n & 31;
        #pragma unroll
        for (int c8 = 0; c8 < 8; ++c8) {
            short8 h8, l8;
            #pragma unroll
            for (int k = 0; k < 8; ++k) {
                const int c = cq * 64 + c8 * 8 + k;
                const float v = Wsrc[c * 32 + nn];
                const unsigned short h = f2bf(v);
                h8[k] = (short)h;
                l8[k] = (short)f2bf(v - bf2f(h));
            }
            *(short8*)(Wfg_hi + n * 256 + cq * 64 + c8 * 8) = h8;
            *(short8*)(Wfg_lo + n * 256 + cq * 64 + c8 * 8) = l8;
        }
    }
}

// ---------------- KA: f,g via split-bf16 MFMA + partial s (fp32) ----------------
__global__ __launch_bounds__(256, 2) void ka(const float* __restrict__ x,
                                             const unsigned short* __restrict__ Wfg_hi,
                                             const unsigned short* __restrict__ Wfg_lo,
                                             const float* __restrict__ bfv,
                                             const float* __restrict__ bgv,
                                             float* __restrict__ s_part) {
    __shared__ __align__(16) unsigned char smem[65536];   // xhi [0,32K), xlo [32K,64K)

    const int t = threadIdx.x, w = t >> 6, l = t & 63;
    const int p = blockIdx.x * 4 + w;      // pixel per wave

    // ---- stage x tile as bf16 hi/lo, XOR-swizzled rows ----
    f4 xr[16];
    #pragma unroll
    for (int j = 0; j < 16; ++j)
        xr[j] = *(const f4*)(x + (((j << 12) + p) << 8) + l * 4);
    #pragma unroll
    for (int j = 0; j < 16; ++j) {
        const int r = j * 4 + w;
        int bo = r * 512 + l * 8;
        bo ^= (r & 7) << 4;
        const unsigned short h0 = f2bf(xr[j][0]), h1 = f2bf(xr[j][1]);
        const unsigned short h2 = f2bf(xr[j][2]), h3 = f2bf(xr[j][3]);
        u32x2 ph, pl;
        ph[0] = ((unsigned)h1 << 16) | h0;
        ph[1] = ((unsigned)h3 << 16) | h2;
        const unsigned short e0 = f2bf(xr[j][0] - bf2f(h0));
        const unsigned short e1 = f2bf(xr[j][1] - bf2f(h1));
        const unsigned short e2 = f2bf(xr[j][2] - bf2f(h2));
        const unsigned short e3 = f2bf(xr[j][3] - bf2f(h3));
        pl[0] = ((unsigned)e1 << 16) | e0;
        pl[1] = ((unsigned)e3 << 16) | e2;
        *(u32x2*)(smem + bo)         = ph;
        *(u32x2*)(smem + 32768 + bo) = pl;
    }
    __syncthreads();

    // ---- MFMA: wave owns 16 N-cols (ncol); 3-term split correction ----
    const int lrow = l & 15;
    const int kfe  = (l >> 4) * 8;
    const int ncol = w * 16 + lrow;
    f32x4 acc[4];
    #pragma unroll
    for (int mt = 0; mt < 4; ++mt) acc[mt] = (f32x4){0.f, 0.f, 0.f, 0.f};

    #pragma unroll
    for (int k0 = 0; k0 < 256; k0 += 32) {
        const short8 bh_ = *(const short8*)(Wfg_hi + ncol * 256 + k0 + kfe);
        const short8 bl_ = *(const short8*)(Wfg_lo + ncol * 256 + k0 + kfe);
        short8 ah[4], al[4];
        #pragma unroll
        for (int mt = 0; mt < 4; ++mt) {
            const int row = mt * 16 + lrow;
            int bo = row * 512 + (k0 + kfe) * 2;
            bo ^= (row & 7) << 4;
            ah[mt] = *(const short8*)(smem + bo);
            al[mt] = *(const short8*)(smem + 32768 + bo);
        }
        #pragma unroll
        for (int mt = 0; mt < 4; ++mt) {
            acc[mt] = __builtin_amdgcn_mfma_f32_16x16x32_bf16(ah[mt], bh_, acc[mt], 0, 0, 0);
            acc[mt] = __builtin_amdgcn_mfma_f32_16x16x32_bf16(al[mt], bh_, acc[mt], 0, 0, 0);
            acc[mt] = __builtin_amdgcn_mfma_f32_16x16x32_bf16(ah[mt], bl_, acc[mt], 0, 0, 0);
        }
    }
    __syncthreads();

    // ---- write F/G (+bias) to LDS (aliases xhi), stride 68 floats ----
    float* FG = (float*)smem;
    const float bias = (ncol < 32) ? bfv[ncol] : bgv[ncol - 32];
    #pragma unroll
    for (int mt = 0; mt < 4; ++mt)
        #pragma unroll
        for (int jj = 0; jj < 4; ++jj) {
            const int row = mt * 16 + (l >> 4) * 4 + jj;
            FG[row * 68 + ncol] = acc[mt][jj] + bias;
        }
    __syncthreads();

    // ---- partial s[i][j] over this block's 4 pixels (fp32) ----
    const int si = t >> 4, sj = t & 15;
    float sacc = 0.f;
    #pragma unroll
    for (int q = 0; q < 4; ++q) {
        const float* Gp = FG + (si * 4 + q) * 68 + 32;
        const float* Fp = FG + (sj * 4 + q) * 68;
        #pragma unroll
        for (int d4 = 0; d4 < 8; ++d4) {
            f4 gv = *(const f4*)(Gp + d4 * 4);
            f4 fv = *(const f4*)(Fp + d4 * 4);
            sacc += gv[0] * fv[0] + gv[1] * fv[1] + gv[2] * fv[2] + gv[3] * fv[3];
        }
    }
    s_part[blockIdx.x * 256 + si * 16 + sj] = sacc;
}

// ---------------- KB1: parallel reduce 1024 partials -> 64 ----------------
__global__ __launch_bounds__(256) void kb1(const float* __restrict__ s_part,
                                           float* __restrict__ s_red) {
    const int t = threadIdx.x, b = blockIdx.x;
    float a = 0.f;
    #pragma unroll
    for (int k = 0; k < 16; ++k) a += s_part[(b * 16 + k) * 256 + t];
    s_red[b * 256 + t] = a;
}

// ---------------- KB2: reduce 64 partials + softmax -> beta ----------------
__global__ __launch_bounds__(1024) void kb2(const float* __restrict__ s_red,
                                            float* __restrict__ beta) {
    __shared__ float red[4 * 256];
    __shared__ float srow[256];
    __shared__ float erow[256];
    const int t = threadIdx.x;
    const int pair = t & 255;
    const int qr = t >> 8;       // 0..3
    float a = 0.f;
    #pragma unroll
    for (int b = qr * 16; b < qr * 16 + 16; ++b) a += s_red[b * 256 + pair];
    red[qr * 256 + pair] = a;
    __syncthreads();
    float s = 0.f, e = 0.f;
    if (t < 256) {
        s = red[pair] + red[256 + pair] + red[512 + pair] + red[768 + pair];
        srow[pair] = s;
    }
    __syncthreads();
    if (t < 256) {
        const int i = pair >> 4;
        float m = srow[i * 16];
        #pragma unroll
        for (int j = 1; j < 16; ++j) m = fmaxf(m, srow[i * 16 + j]);
        e = expf(s - m);
        erow[pair] = e;
    }
    __syncthreads();
    if (t < 256) {
        const int i = pair >> 4;
        float sum = 0.f;
        #pragma unroll
        for (int j = 0; j < 16; ++j) sum += erow[i * 16 + j];
        beta[pair] = e / sum;
    }
}

// ---------------- KC: 1 wave = 1 pixel, ZERO barriers ----------------
// grid 4096 x 64 threads. Wave owns pixel p end-to-end:
//   load x(16 f4) -> mix (beta from LDS) -> bf16 xm into private 8KB LDS tile
//   -> GEMM M=16,N=256,K=256 (A from LDS, B streamed from L2 WhT, 2-deep prefetch)
//   -> epilogue: C transposed through same LDS tile (2 halves), f4 residual re-read
//      (x is L3-resident), NT f4 stores.
// All LDS deps are intra-wave (in-order LDS pipe) -> no __syncthreads anywhere.
// 9.25 KB LDS + <=128 VGPR -> 16 independent waves/CU at staggered phases.
__global__ __launch_bounds__(64, 4) void kc(const float* __restrict__ x,
                                            const unsigned short* __restrict__ WhT,
                                            const float* __restrict__ gb,
                                            const float* __restrict__ beta,
                                            float* __restrict__ out) {
    __shared__ __align__(16) unsigned char smem[9216];   // xm/cst tile 8192 | beta 1024
    float* beta_l = (float*)(smem + 8192);

    const int l = threadIdx.x;          // 0..63
    const int p = blockIdx.x;           // pixel
    const int cbase = l * 4;
    const int lrow = l & 15;
    const int hi   = l >> 4;

    // ---- beta -> LDS (single wave: no barrier, lgkmcnt only) ----
    *(f4*)(beta_l + l * 4) = *(const f4*)(beta + l * 4);

    // ---- load x[j][p][cbase..+3] ----
    f4 xr[16];
    #pragma unroll
    for (int j = 0; j < 16; ++j)
        xr[j] = *(const f4*)(x + (((j << 12) + p) << 8) + cbase);

    // ---- mix: xm[i][cbase..+3] = sum_j beta[i][j]*xr[j]; bf16 -> swizzled LDS ----
    #pragma unroll
    for (int i = 0; i < 16; ++i) {
        f4 bv0 = *(const f4*)(beta_l + i * 16);
        f4 bv1 = *(const f4*)(beta_l + i * 16 + 4);
        f4 bv2 = *(const f4*)(beta_l + i * 16 + 8);
        f4 bv3 = *(const f4*)(beta_l + i * 16 + 12);
        f4 a = {0.f, 0.f, 0.f, 0.f};
        #pragma unroll
        for (int j = 0; j < 4; ++j) {
            a += xr[j]      * bv0[j];
            a += xr[4 + j]  * bv1[j];
            a += xr[8 + j]  * bv2[j];
            a += xr[12 + j] * bv3[j];
        }
        int bo = i * 512 + l * 8;
        bo ^= (i & 7) << 4;                      // XOR swizzle (T2)
        u32x2 packed;
        packed[0] = ((unsigned)f2bf(a[1]) << 16) | f2bf(a[0]);
        packed[1] = ((unsigned)f2bf(a[3]) << 16) | f2bf(a[2]);
        *(u32x2*)(smem + bo) = packed;
    }

    // ---- GEMM: [16 x 256(k)] @ WhT -> all 256 d-cols in this wave ----
    f32x4 acc[16];
    #pragma unroll
    for (int nt = 0; nt < 16; ++nt) acc[nt] = (f32x4){0.f, 0.f, 0.f, 0.f};

    #pragma unroll
    for (int kh = 0; kh < 2; ++kh) {
        // A-fragments for this k-half (4 x b128 from swizzled LDS)
        short8 af[4];
        #pragma unroll
        for (int ks = 0; ks < 4; ++ks) {
            const int kb = kh * 128 + ks * 32;
            int bo = lrow * 512 + (kb + hi * 8) * 2;
            bo ^= (lrow & 7) << 4;
            af[ks] = *(const short8*)(smem + bo);
        }
        // B stream: q = nt*4+ks flattened, 2-deep prefetch, all static post-unroll
        const unsigned short* wb = WhT + lrow * 256 + kh * 128 + hi * 8;
        short8 bpre[2];
        bpre[0] = *(const short8*)(wb);                      // q=0: nt0,ks0
        bpre[1] = *(const short8*)(wb + 32);                 // q=1: nt0,ks1
        #pragma unroll
        for (int q = 0; q < 64; ++q) {
            short8 bc = bpre[q & 1];
            if (q + 2 < 64) {
                const int qn = q + 2;
                bpre[q & 1] = *(const short8*)(wb + (qn >> 2) * (16 * 256) + (qn & 3) * 32);
            }
            acc[q >> 2] = __builtin_amdgcn_mfma_f32_16x16x32_bf16(
                af[q & 3], bc, acc[q >> 2], 0, 0, 0);
        }
    }

    // ---- epilogue: 2 halves of 128 cols; transpose C through same LDS tile ----
    #pragma unroll
    for (int h = 0; h < 2; ++h) {
        // write C (f32) at [i][c'] (row stride 512B), swizzled
        #pragma unroll
        for (int nt2 = 0; nt2 < 8; ++nt2) {
            const int nt = h * 8 + nt2;
            #pragma unroll
            for (int j = 0; j < 4; ++j) {
                const int i = hi * 4 + j;
                int ad = i * 512 + (nt2 * 16 + lrow) * 4;
                ad ^= (i & 7) << 4;
                *(float*)(smem + ad) = acc[nt][j];
            }
        }
        // read back f4, add gamma*bh + x residual (L3-hit), NT store
        #pragma unroll
        for (int rr = 0; rr < 8; ++rr) {
            const int i = rr * 2 + (l >> 5);
            int ad = i * 512 + (l & 31) * 16;
            ad ^= (i & 7) << 4;
            f4 o = *(const f4*)(smem + ad);
            const int c = h * 128 + (l & 31) * 4;
            const int idx = (((i << 12) + p) << 8) + c;
            o += *(const f4*)(gb + c) + *(const f4*)(x + idx);
            __builtin_nontemporal_store(o, (f4*)(out + idx));
        }
    }
}

extern "C" void kernel_launch(void* const* d_in, const int* in_sizes, int n_in,
                              void* d_out, int out_size, void* d_ws, size_t ws_size,
                              hipStream_t stream) {
    const float* x     = (const float*)d_in[0];
    const float* Wf    = (const float*)d_in[1];
    const float* Wg    = (const float*)d_in[2];
    const float* Wh    = (const float*)d_in[3];
    const float* bfv   = (const float*)d_in[4];
    const float* bgv   = (const float*)d_in[5];
    const float* bhv   = (const float*)d_in[6];
    const float* gamma = (const float*)d_in[7];
    float* out = (float*)d_out;

    char* ws = (char*)d_ws;
    unsigned short* WhT = (unsigned short*)ws;                 // 131072 B
    float* gb     = (float*)(ws + 131072);                     // 1024 B
    float* beta   = (float*)(ws + 132096);                     // 1024 B
    float* s_part = (float*)(ws + 133120);                     // 1024*256*4 = 1 MB
    unsigned short* Wfg_hi = (unsigned short*)(ws + 1181696);  // 32768 B
    unsigned short* Wfg_lo = (unsigned short*)(ws + 1214464);  // 32768 B
    // s_red reuses the Wfg region (dead after ka completes, rewritten by k_setup each call)
    float* s_red  = (float*)(ws + 1181696);                    // 64*256*4 = 65536 B

    k_setup<<<dim3(33), dim3(256), 0, stream>>>(Wh, bhv, Wf, Wg, gamma, WhT, gb, Wfg_hi, Wfg_lo);
    ka<<<dim3(1024), dim3(256), 0, stream>>>(x, Wfg_hi, Wfg_lo, bfv, bgv, s_part);
    kb1<<<dim3(64), dim3(256), 0, stream>>>(s_part, s_red);
    kb2<<<dim3(1), dim3(1024), 0, stream>>>(s_red, beta);
    kc<<<dim3(4096), dim3(64), 0, stream>>>(x, WhT, gb, beta, out);
}

// Round 10
// 99.179 us; speedup vs baseline: 1.2596x; 1.2596x over previous
//
#include <hip/hip_runtime.h>

typedef __attribute__((ext_vector_type(4))) float  f4;
typedef __attribute__((ext_vector_type(2))) float  f2;
typedef __attribute__((ext_vector_type(8))) short  short8;
typedef __attribute__((ext_vector_type(4))) float  f32x4;
typedef __attribute__((ext_vector_type(2))) unsigned int u32x2;

static __device__ __forceinline__ unsigned short f2bf(float f) {
    unsigned u = __builtin_bit_cast(unsigned, f);
    unsigned r = (u + 0x7FFFu + ((u >> 16) & 1u)) >> 16;   // RNE
    return (unsigned short)r;
}
static __device__ __forceinline__ float bf2f(unsigned short h) {
    return __builtin_bit_cast(float, ((unsigned)h) << 16);
}

// ---------------- K0: WhT[d][c]=bf16(g*Wh[c][d]); gb=g*bh; WfgT hi/lo split ----------------
__global__ __launch_bounds__(256) void k_setup(const float* __restrict__ Wh,
                                               const float* __restrict__ bh,
                                               const float* __restrict__ Wf,
                                               const float* __restrict__ Wg,
                                               const float* __restrict__ gamma,
                                               unsigned short* __restrict__ WhT,
                                               float* __restrict__ gb,
                                               unsigned short* __restrict__ Wfg_hi,
                                               unsigned short* __restrict__ Wfg_lo) {
    __shared__ float T[8 * 260];
    const int t = threadIdx.x, b = blockIdx.x;
    const float g = gamma[0];
    if (b < 32) {
        const int c0 = b * 8;
        const int cr = t >> 5, q = t & 31;
        f4 v0 = *(const f4*)(Wh + (c0 + cr) * 256 + q * 8);
        f4 v1 = *(const f4*)(Wh + (c0 + cr) * 256 + q * 8 + 4);
        *(f4*)(T + cr * 260 + q * 8)     = v0;
        *(f4*)(T + cr * 260 + q * 8 + 4) = v1;
        __syncthreads();
        short8 o;
        #pragma unroll
        for (int j = 0; j < 8; ++j) o[j] = (short)f2bf(g * T[j * 260 + t]);
        *(short8*)(WhT + t * 256 + c0) = o;
    } else {
        gb[t] = g * bh[t];
        const int n = t >> 2, cq = t & 3;
        const float* Wsrc = (n < 32) ? Wf : Wg;
        const int nn = n & 31;
        #pragma unroll
        for (int c8 = 0; c8 < 8; ++c8) {
            short8 h8, l8;
            #pragma unroll
            for (int k = 0; k < 8; ++k) {
                const int c = cq * 64 + c8 * 8 + k;
                const float v = Wsrc[c * 32 + nn];
                const unsigned short h = f2bf(v);
                h8[k] = (short)h;
                l8[k] = (short)f2bf(v - bf2f(h));
            }
            *(short8*)(Wfg_hi + n * 256 + cq * 64 + c8 * 8) = h8;
            *(short8*)(Wfg_lo + n * 256 + cq * 64 + c8 * 8) = l8;
        }
    }
}

// ---------------- KA: f,g via split-bf16 MFMA + partial s (fp32) ----------------
__global__ __launch_bounds__(256, 2) void ka(const float* __restrict__ x,
                                             const unsigned short* __restrict__ Wfg_hi,
                                             const unsigned short* __restrict__ Wfg_lo,
                                             const float* __restrict__ bfv,
                                             const float* __restrict__ bgv,
                                             float* __restrict__ s_part) {
    __shared__ __align__(16) unsigned char smem[65536];   // xhi [0,32K), xlo [32K,64K)

    const int t = threadIdx.x, w = t >> 6, l = t & 63;
    const int p = blockIdx.x * 4 + w;      // pixel per wave

    // ---- stage x tile as bf16 hi/lo, XOR-swizzled rows ----
    f4 xr[16];
    #pragma unroll
    for (int j = 0; j < 16; ++j)
        xr[j] = *(const f4*)(x + (((j << 12) + p) << 8) + l * 4);
    #pragma unroll
    for (int j = 0; j < 16; ++j) {
        const int r = j * 4 + w;
        int bo = r * 512 + l * 8;
        bo ^= (r & 7) << 4;
        const unsigned short h0 = f2bf(xr[j][0]), h1 = f2bf(xr[j][1]);
        const unsigned short h2 = f2bf(xr[j][2]), h3 = f2bf(xr[j][3]);
        u32x2 ph, pl;
        ph[0] = ((unsigned)h1 << 16) | h0;
        ph[1] = ((unsigned)h3 << 16) | h2;
        const unsigned short e0 = f2bf(xr[j][0] - bf2f(h0));
        const unsigned short e1 = f2bf(xr[j][1] - bf2f(h1));
        const unsigned short e2 = f2bf(xr[j][2] - bf2f(h2));
        const unsigned short e3 = f2bf(xr[j][3] - bf2f(h3));
        pl[0] = ((unsigned)e1 << 16) | e0;
        pl[1] = ((unsigned)e3 << 16) | e2;
        *(u32x2*)(smem + bo)         = ph;
        *(u32x2*)(smem + 32768 + bo) = pl;
    }
    __syncthreads();

    // ---- MFMA: wave owns 16 N-cols (ncol); 3-term split correction ----
    const int lrow = l & 15;
    const int kfe  = (l >> 4) * 8;
    const int ncol = w * 16 + lrow;
    f32x4 acc[4];
    #pragma unroll
    for (int mt = 0; mt < 4; ++mt) acc[mt] = (f32x4){0.f, 0.f, 0.f, 0.f};

    #pragma unroll
    for (int k0 = 0; k0 < 256; k0 += 32) {
        const short8 bh_ = *(const short8*)(Wfg_hi + ncol * 256 + k0 + kfe);
        const short8 bl_ = *(const short8*)(Wfg_lo + ncol * 256 + k0 + kfe);
        short8 ah[4], al[4];
        #pragma unroll
        for (int mt = 0; mt < 4; ++mt) {
            const int row = mt * 16 + lrow;
            int bo = row * 512 + (k0 + kfe) * 2;
            bo ^= (row & 7) << 4;
            ah[mt] = *(const short8*)(smem + bo);
            al[mt] = *(const short8*)(smem + 32768 + bo);
        }
        #pragma unroll
        for (int mt = 0; mt < 4; ++mt) {
            acc[mt] = __builtin_amdgcn_mfma_f32_16x16x32_bf16(ah[mt], bh_, acc[mt], 0, 0, 0);
            acc[mt] = __builtin_amdgcn_mfma_f32_16x16x32_bf16(al[mt], bh_, acc[mt], 0, 0, 0);
            acc[mt] = __builtin_amdgcn_mfma_f32_16x16x32_bf16(ah[mt], bl_, acc[mt], 0, 0, 0);
        }
    }
    __syncthreads();

    // ---- write F/G (+bias) to LDS (aliases xhi), stride 68 floats ----
    float* FG = (float*)smem;
    const float bias = (ncol < 32) ? bfv[ncol] : bgv[ncol - 32];
    #pragma unroll
    for (int mt = 0; mt < 4; ++mt)
        #pragma unroll
        for (int jj = 0; jj < 4; ++jj) {
            const int row = mt * 16 + (l >> 4) * 4 + jj;
            FG[row * 68 + ncol] = acc[mt][jj] + bias;
        }
    __syncthreads();

    // ---- partial s[i][j] over this block's 4 pixels (fp32) ----
    const int si = t >> 4, sj = t & 15;
    float sacc = 0.f;
    #pragma unroll
    for (int q = 0; q < 4; ++q) {
        const float* Gp = FG + (si * 4 + q) * 68 + 32;
        const float* Fp = FG + (sj * 4 + q) * 68;
        #pragma unroll
        for (int d4 = 0; d4 < 8; ++d4) {
            f4 gv = *(const f4*)(Gp + d4 * 4);
            f4 fv = *(const f4*)(Fp + d4 * 4);
            sacc += gv[0] * fv[0] + gv[1] * fv[1] + gv[2] * fv[2] + gv[3] * fv[3];
        }
    }
    s_part[blockIdx.x * 256 + si * 16 + sj] = sacc;
}

// ---------------- KB1: parallel reduce 1024 partials -> 64 ----------------
__global__ __launch_bounds__(256) void kb1(const float* __restrict__ s_part,
                                           float* __restrict__ s_red) {
    const int t = threadIdx.x, b = blockIdx.x;
    float a = 0.f;
    #pragma unroll
    for (int k = 0; k < 16; ++k) a += s_part[(b * 16 + k) * 256 + t];
    s_red[b * 256 + t] = a;
}

// ---------------- KB2: reduce 64 partials + softmax -> beta ----------------
__global__ __launch_bounds__(1024) void kb2(const float* __restrict__ s_red,
                                            float* __restrict__ beta) {
    __shared__ float red[4 * 256];
    __shared__ float srow[256];
    __shared__ float erow[256];
    const int t = threadIdx.x;
    const int pair = t & 255;
    const int qr = t >> 8;       // 0..3
    float a = 0.f;
    #pragma unroll
    for (int b = qr * 16; b < qr * 16 + 16; ++b) a += s_red[b * 256 + pair];
    red[qr * 256 + pair] = a;
    __syncthreads();
    float s = 0.f, e = 0.f;
    if (t < 256) {
        s = red[pair] + red[256 + pair] + red[512 + pair] + red[768 + pair];
        srow[pair] = s;
    }
    __syncthreads();
    if (t < 256) {
        const int i = pair >> 4;
        float m = srow[i * 16];
        #pragma unroll
        for (int j = 1; j < 16; ++j) m = fmaxf(m, srow[i * 16 + j]);
        e = expf(s - m);
        erow[pair] = e;
    }
    __syncthreads();
    if (t < 256) {
        const int i = pair >> 4;
        float sum = 0.f;
        #pragma unroll
        for (int j = 0; j < 16; ++j) sum += erow[i * 16 + j];
        beta[pair] = e / sum;
    }
}

// ---------------- KC helpers ----------------
__device__ __forceinline__ void kc_mix(const f4 (&xr)[16], const float* beta_l,
                                       unsigned char* stage, int w, int l) {
    #pragma unroll
    for (int i = 0; i < 16; ++i) {
        f4 bv0 = *(const f4*)(beta_l + i * 16);        // broadcast reads
        f4 bv1 = *(const f4*)(beta_l + i * 16 + 4);
        f4 bv2 = *(const f4*)(beta_l + i * 16 + 8);
        f4 bv3 = *(const f4*)(beta_l + i * 16 + 12);
        f4 a = {0.f, 0.f, 0.f, 0.f};
        #pragma unroll
        for (int j = 0; j < 4; ++j) {
            a += xr[j]      * bv0[j];
            a += xr[4 + j]  * bv1[j];
            a += xr[8 + j]  * bv2[j];
            a += xr[12 + j] * bv3[j];
        }
        const int r = i * 4 + w;
        int bo = r * 512 + l * 8;
        bo ^= (r & 7) << 4;                      // XOR swizzle (T2)
        u32x2 packed;
        packed[0] = ((unsigned)f2bf(a[1]) << 16) | f2bf(a[0]);
        packed[1] = ((unsigned)f2bf(a[3]) << 16) | f2bf(a[2]);
        *(u32x2*)(stage + bo) = packed;
    }
}

__device__ __forceinline__ void kc_gemm(f32x4 (&acc)[4][4], const unsigned char* stage,
                                        const unsigned short* wbase, int lrow, int kf) {
    #pragma unroll
    for (int mt = 0; mt < 4; ++mt)
        #pragma unroll
        for (int nt = 0; nt < 4; ++nt) acc[mt][nt] = (f32x4){0.f, 0.f, 0.f, 0.f};

    short8 bcur[4], bnxt[4];
    #pragma unroll
    for (int nt = 0; nt < 4; ++nt)
        bcur[nt] = *(const short8*)(wbase + nt * 16 * 256);

    #pragma unroll
    for (int ks = 0; ks < 8; ++ks) {
        const int k0 = ks * 32;
        if (ks < 7) {
            #pragma unroll
            for (int nt = 0; nt < 4; ++nt)
                bnxt[nt] = *(const short8*)(wbase + nt * 16 * 256 + k0 + 32);
        }
        short8 af[4];
        #pragma unroll
        for (int mt = 0; mt < 4; ++mt) {
            const int row = mt * 16 + lrow;
            int bo = row * 512 + (k0 + kf) * 2;
            bo ^= (row & 7) << 4;
            af[mt] = *(const short8*)(stage + bo);
        }
        #pragma unroll
        for (int mt = 0; mt < 4; ++mt)
            #pragma unroll
            for (int nt = 0; nt < 4; ++nt)
                acc[mt][nt] = __builtin_amdgcn_mfma_f32_16x16x32_bf16(
                    af[mt], bcur[nt], acc[mt][nt], 0, 0, 0);
        #pragma unroll
        for (int nt = 0; nt < 4; ++nt) bcur[nt] = bnxt[nt];
    }
}

// ---------------- KC1: mix streamer -> bf16 swizzled LDS-image in ws ----------------
// grid 1024 x 256. Block b = pixels 4b..4b+3; wave w owns pixel p0+w.
// Pure stream: no RAW deps, no GEMM. Writes the byte-exact LDS image kc2 will copy.
__global__ __launch_bounds__(256, 4) void kc1(const float* __restrict__ x,
                                              const float* __restrict__ beta,
                                              unsigned char* __restrict__ xmimg) {
    __shared__ float beta_l[256];
    const int t = threadIdx.x, w = t >> 6, l = t & 63;
    const int p = blockIdx.x * 4 + w;
    const int cbase = l * 4;

    f4 xr[16];
    #pragma unroll
    for (int j = 0; j < 16; ++j)
        xr[j] = *(const f4*)(x + (((j << 12) + p) << 8) + cbase);
    if (t < 64) *(f4*)(beta_l + t * 4) = *(const f4*)(beta + t * 4);
    __syncthreads();

    kc_mix(xr, beta_l, xmimg + (size_t)blockIdx.x * 32768, w, l);
}

// ---------------- KC2: image -> LDS copy + GEMM + residual epilogue ----------------
// grid 1024 x 256 (4 waves). No mix, no xr -> VGPRs free for prefetch.
__global__ __launch_bounds__(256, 4) void kc2(const float* __restrict__ x,
                                              const unsigned short* __restrict__ WhT,
                                              const float* __restrict__ gb,
                                              const unsigned char* __restrict__ xmimg,
                                              float* __restrict__ out) {
    __shared__ __align__(16) unsigned char smem[33024];  // stage 32768 / cst 33024 alias

    const int t = threadIdx.x;
    const int w = t >> 6;
    const int l = t & 63;
    const int p0 = blockIdx.x * 4;
    const int cbase = l * 4;
    const int n0 = w * 64;
    const int lrow = l & 15;
    const int hi = l >> 4;
    const int kf = hi * 8;
    const unsigned short* wbase = WhT + (n0 + lrow) * 256 + kf;

    // ---- copy 32KB image slice to LDS (byte-identical, linear) ----
    {
        const unsigned char* img = xmimg + (size_t)blockIdx.x * 32768;
        f4 v[8];
        #pragma unroll
        for (int k = 0; k < 8; ++k)
            v[k] = *(const f4*)(img + (k * 256 + t) * 16);
        #pragma unroll
        for (int k = 0; k < 8; ++k)
            *(f4*)(smem + (k * 256 + t) * 16) = v[k];
    }
    __syncthreads();

    f32x4 acc[4][4];
    kc_gemm(acc, smem, wbase, lrow, kf);

    // ---- epilogue: hoisted residual-x loads; LDS-transpose; NT stores ----
    float* cst = (float*)smem;                 // [32][258]
    const f4 gb4 = *(const f4*)(gb + cbase);
    #pragma unroll
    for (int h = 0; h < 2; ++h) {
        f4 xa[8];
        #pragma unroll
        for (int rr = 0; rr < 8; ++rr) {       // issue early: complete under barriers
            const int rg = h * 32 + rr * 4 + w;
            const int i  = rg >> 2, q = rg & 3;
            xa[rr] = *(const f4*)(x + (((i << 12) + p0 + q) << 8) + cbase);
        }
        __syncthreads();
        #pragma unroll
        for (int mt2 = 0; mt2 < 2; ++mt2) {
            const int mt = h * 2 + mt2;
            #pragma unroll
            for (int nt = 0; nt < 4; ++nt)
                #pragma unroll
                for (int j = 0; j < 4; ++j) {
                    const int rl = mt2 * 16 + hi * 4 + j;
                    cst[rl * 258 + n0 + nt * 16 + lrow] = acc[mt][nt][j];
                }
        }
        __syncthreads();
        #pragma unroll
        for (int rr = 0; rr < 8; ++rr) {
            const int rl = rr * 4 + w;          // local row 0..31
            const int rg = h * 32 + rl;
            const int i  = rg >> 2, q = rg & 3;
            const int idx = (((i << 12) + p0 + q) << 8) + cbase;
            f4 o = *(const f4*)(cst + rl * 258 + cbase);
            o += gb4 + xa[rr];
            __builtin_nontemporal_store(o, (f4*)(out + idx));
        }
    }
}

// ---------------- KC fused fallback (R7 structure) if ws too small ----------------
__global__ __launch_bounds__(256, 3) void kc_fused(const float* __restrict__ x,
                                                   const unsigned short* __restrict__ WhT,
                                                   const float* __restrict__ gb,
                                                   const float* __restrict__ beta,
                                                   float* __restrict__ out) {
    __shared__ __align__(16) unsigned char smem[34048];
    float* beta_l = (float*)(smem + 33024);

    const int t = threadIdx.x;
    const int w = t >> 6;
    const int l = t & 63;
    const int p0 = blockIdx.x * 4;
    const int p  = p0 + w;
    const int cbase = l * 4;
    const int n0 = w * 64;
    const int lrow = l & 15;
    const int hi = l >> 4;
    const int kf = hi * 8;
    const unsigned short* wbase = WhT + (n0 + lrow) * 256 + kf;

    f4 xr[16];
    #pragma unroll
    for (int j = 0; j < 16; ++j)
        xr[j] = *(const f4*)(x + (((j << 12) + p) << 8) + cbase);
    if (t < 64) *(f4*)(beta_l + t * 4) = *(const f4*)(beta + t * 4);
    __syncthreads();

    kc_mix(xr, beta_l, smem, w, l);
    __syncthreads();

    f32x4 acc[4][4];
    kc_gemm(acc, smem, wbase, lrow, kf);

    float* cst = (float*)smem;
    const f4 gb4 = *(const f4*)(gb + cbase);
    #pragma unroll
    for (int h = 0; h < 2; ++h) {
        __syncthreads();
        #pragma unroll
        for (int mt2 = 0; mt2 < 2; ++mt2) {
            const int mt = h * 2 + mt2;
            #pragma unroll
            for (int nt = 0; nt < 4; ++nt)
                #pragma unroll
                for (int j = 0; j < 4; ++j) {
                    const int rl = mt2 * 16 + hi * 4 + j;
                    cst[rl * 258 + n0 + nt * 16 + lrow] = acc[mt][nt][j];
                }
        }
        __syncthreads();
        #pragma unroll
        for (int rr = 0; rr < 8; ++rr) {
            const int rl = rr * 4 + w;
            const int rg = h * 32 + rl;
            const int i  = rg >> 2, q = rg & 3;
            const int idx = (((i << 12) + p0 + q) << 8) + cbase;
            f4 o = *(const f4*)(cst + rl * 258 + cbase);
            o += gb4 + *(const f4*)(x + idx);
            __builtin_nontemporal_store(o, (f4*)(out + idx));
        }
    }
}

extern "C" void kernel_launch(void* const* d_in, const int* in_sizes, int n_in,
                              void* d_out, int out_size, void* d_ws, size_t ws_size,
                              hipStream_t stream) {
    const float* x     = (const float*)d_in[0];
    const float* Wf    = (const float*)d_in[1];
    const float* Wg    = (const float*)d_in[2];
    const float* Wh    = (const float*)d_in[3];
    const float* bfv   = (const float*)d_in[4];
    const float* bgv   = (const float*)d_in[5];
    const float* bhv   = (const float*)d_in[6];
    const float* gamma = (const float*)d_in[7];
    float* out = (float*)d_out;

    char* ws = (char*)d_ws;
    unsigned short* WhT = (unsigned short*)ws;                 // 131072 B
    float* gb     = (float*)(ws + 131072);                     // 1024 B
    float* beta   = (float*)(ws + 132096);                     // 1024 B
    float* s_part = (float*)(ws + 133120);                     // 1024*256*4 = 1 MB
    unsigned short* Wfg_hi = (unsigned short*)(ws + 1181696);  // 32768 B
    unsigned short* Wfg_lo = (unsigned short*)(ws + 1214464);  // 32768 B
    float* s_red  = (float*)(ws + 1181696);                    // reuses Wfg region
    unsigned char* xmimg = (unsigned char*)(ws + 2097152);     // 32 MB bf16 image

    k_setup<<<dim3(33), dim3(256), 0, stream>>>(Wh, bhv, Wf, Wg, gamma, WhT, gb, Wfg_hi, Wfg_lo);
    ka<<<dim3(1024), dim3(256), 0, stream>>>(x, Wfg_hi, Wfg_lo, bfv, bgv, s_part);
    kb1<<<dim3(64), dim3(256), 0, stream>>>(s_part, s_red);
    kb2<<<dim3(1), dim3(1024), 0, stream>>>(s_red, beta);

    if (ws_size >= 2097152ull + 33554432ull) {
        kc1<<<dim3(1024), dim3(256), 0, stream>>>(x, beta, xmimg);
        kc2<<<dim3(1024), dim3(256), 0, stream>>>(x, WhT, gb, xmimg, out);
    } else {
        kc_fused<<<dim3(1024), dim3(256), 0, stream>>>(x, WhT, gb, beta, out);
    }
}